// Round 2
// baseline (124.847 us; speedup 1.0000x reference)
//
#include <hip/hip_runtime.h>

// Problem constants (fixed by setup_inputs)
#define NB 16
#define NS 8
#define NPTS 131072
#define NA 18

#define THREADS 256
#define WAVES (THREADS / 64)
#define CHUNKS 64
#define ELEMS (NPTS / CHUNKS)          // 2048 points per block
#define PT_PER_WAVE (ELEMS / WAVES)    // 512 points per wave
#define ITERS (PT_PER_WAVE / 32)       // 16 iters (8 lanes/group x 4 pts/float4)

#define PARTIALS 72                    // 8 rows x (8 bins + tsum)
// ws layout (floats): partials[NB*CHUNKS][72], then 32 DP results
#define WS_RES (NB * CHUNKS * PARTIALS)

__device__ __forceinline__ void proc_elem(float x, int m, float acc[8], float& tsum) {
    // x = log(p); reference: lgp = max(x, -100), lg1m = max(log1p(-exp(x)), -100)
    float lgp  = fmaxf(x, -100.0f);
    float e    = __expf(x);
    float lg1m = fmaxf(__logf(1.0f - e), -100.0f);
    float d    = lgp - lg1m;
    tsum += lg1m;
#pragma unroll
    for (int j = 0; j < 8; ++j) acc[j] += (m == j) ? d : 0.0f;
}

// One block per (b, chunk); within each wave, 8-lane group g handles row g.
// Mask is loaded once (identical addresses across groups -> L1 broadcast).
__global__ __launch_bounds__(THREADS) void seg_accum_kernel(
    const float* __restrict__ logp, const int* __restrict__ mask,
    float* __restrict__ ws) {
    const int chunk = blockIdx.x;
    const int b = blockIdx.y;
    const int tid = (int)threadIdx.x;
    const int wave = tid >> 6;
    const int lane = tid & 63;
    const int g = lane >> 3;   // row index this lane accumulates
    const int t = lane & 7;

    const int ptbase = chunk * ELEMS + wave * PT_PER_WAVE;
    const int4*   m4  = (const int4*)(mask + (size_t)b * NPTS + ptbase);
    const float4* lp4 = (const float4*)(logp + ((size_t)(b * NS + g)) * NPTS + ptbase);

    float acc[8] = {0.f, 0.f, 0.f, 0.f, 0.f, 0.f, 0.f, 0.f};
    float ts = 0.f;

#pragma unroll
    for (int it = 0; it < ITERS; ++it) {
        const int idx = it * 8 + t;          // float4/int4 index in the wave's span
        const int4   mm = m4[idx];           // same across all 8 groups
        const float4 lp = lp4[idx];
        proc_elem(lp.x, mm.x, acc, ts);
        proc_elem(lp.y, mm.y, acc, ts);
        proc_elem(lp.z, mm.z, acc, ts);
        proc_elem(lp.w, mm.w, acc, ts);
    }

    // reduce across the 8 lanes of the group (shuffle down 4,2,1)
#pragma unroll
    for (int off = 4; off > 0; off >>= 1) {
#pragma unroll
        for (int j = 0; j < 8; ++j) acc[j] += __shfl_down(acc[j], off);
        ts += __shfl_down(ts, off);
    }

    __shared__ float red[WAVES][NS][9];
    if (t == 0) {
#pragma unroll
        for (int j = 0; j < 8; ++j) red[wave][g][j] = acc[j];
        red[wave][g][8] = ts;
    }
    __syncthreads();

    if (tid < PARTIALS) {
        const int gg = tid / 9, jj = tid % 9;
        float v = red[0][gg][jj] + red[1][gg][jj] + red[2][gg][jj] + red[3][gg][jj];
        ws[((size_t)(b * CHUNKS + chunk)) * PARTIALS + tid] = v;
    }
}

// 32 blocks (b, which) x 64 threads: build 8x8 cost matrix, assignment DP.
// Writes per-(b,w) optimal cost to res[bw] (no atomics, no zero-init needed).
__global__ __launch_bounds__(64) void assign_kernel(
    const float* __restrict__ parts, const float* __restrict__ pred_aff,
    const int* __restrict__ gt_aff, float* __restrict__ res) {
    const int bw = blockIdx.x;
    const int b = bw >> 1;
    const int w = bw & 1;          // 0 = seg, 1 = aff
    const int lane = (int)threadIdx.x;
    const int i = lane >> 3, j = lane & 7;

    __shared__ float cost[8][8];
    __shared__ float dp[256];

    float c;
    if (w == 0) {
        float sp = 0.f, tt = 0.f;
        for (int cch = 0; cch < CHUNKS; ++cch) {
            const float* p = parts + ((size_t)(b * CHUNKS + cch)) * PARTIALS;
            sp += p[i * 9 + j];
            tt += p[i * 9 + 8];
        }
        c = -(sp + tt) * (1.0f / (float)NPTS);
    } else {
        float a = 0.f;
#pragma unroll
        for (int k = 0; k < NA; ++k) {
            float p = pred_aff[((b * NS + i) * NA) + k];
            float g = (float)gt_aff[((b * NS + j) * NA) + k];
            float lgp = fmaxf(__logf(p), -100.0f);
            float l1m = fmaxf(__logf(1.0f - p), -100.0f);
            a += g * lgp + (1.0f - g) * l1m;
        }
        c = -a * (1.0f / (float)NA);
    }
    cost[i][j] = c;

    dp[lane] = 1e30f; dp[lane + 64] = 1e30f; dp[lane + 128] = 1e30f; dp[lane + 192] = 1e30f;
    __syncthreads();
    if (lane == 0) dp[0] = 0.f;
    __syncthreads();

    // dp[mask] = min cost assigning rows 0..popc(mask)-1 to column set `mask`
    for (int l = 1; l <= 8; ++l) {
#pragma unroll
        for (int base = 0; base < 256; base += 64) {
            const int mm = base + lane;
            if (__popc(mm) == l) {
                float best = 1e30f;
#pragma unroll
                for (int jj = 0; jj < 8; ++jj) {
                    if (mm & (1 << jj))
                        best = fminf(best, dp[mm ^ (1 << jj)] + cost[l - 1][jj]);
                }
                dp[mm] = best;
            }
        }
        __syncthreads();
    }
    if (lane == 0) res[bw] = dp[255];
}

__global__ __launch_bounds__(64) void writeout_kernel(
    const float* __restrict__ res, float* __restrict__ out) {
    const int lane = (int)threadIdx.x;
    float v = (lane < 2 * NB) ? res[lane] : 0.f;
    float segv = ((lane & 1) == 0) ? v : 0.f;
    float affv = ((lane & 1) == 1) ? v : 0.f;
#pragma unroll
    for (int off = 32; off > 0; off >>= 1) {
        segv += __shfl_down(segv, off);
        affv += __shfl_down(affv, off);
    }
    if (lane == 0) {
        const float seg = segv * (1.0f / (float)NB);
        const float aff = affv * (1.0f / (float)NB);
        out[0] = seg;
        out[1] = aff;
        out[2] = aff + 3.0f * seg;
    }
}

extern "C" void kernel_launch(void* const* d_in, const int* in_sizes, int n_in,
                              void* d_out, int out_size, void* d_ws, size_t ws_size,
                              hipStream_t stream) {
    const float* pred_seg_logp = (const float*)d_in[0];
    const float* pred_aff      = (const float*)d_in[1];
    const int*   gt_seg_mask   = (const int*)d_in[2];
    const int*   gt_aff        = (const int*)d_in[3];
    float* out = (float*)d_out;
    float* ws  = (float*)d_ws;

    dim3 grid(CHUNKS, NB);
    seg_accum_kernel<<<grid, THREADS, 0, stream>>>(pred_seg_logp, gt_seg_mask, ws);
    assign_kernel<<<NB * 2, 64, 0, stream>>>(ws, pred_aff, gt_aff, ws + WS_RES);
    writeout_kernel<<<1, 64, 0, stream>>>(ws + WS_RES, out);
}